// Round 1
// baseline (183.984 us; speedup 1.0000x reference)
//
#include <hip/hip_runtime.h>

// Problem constants (match reference): B=1024, L=256, H=128
#define L_ 256
#define H_ 128

__global__ __launch_bounds__(256) void fused_match_kernel(
    const float* __restrict__ team_embed,    // (1000,128)
    const float* __restrict__ venue_embed,   // (3,128)
    const float* __restrict__ result_embed,  // (3,128)
    const float* __restrict__ W_out,         // (517,3)
    const float* __restrict__ b_out,         // (3,)
    const float* __restrict__ goals_for,     // (B,L)
    const float* __restrict__ goals_against, // (B,L)
    const float* __restrict__ stats,         // (B,3)
    const int* __restrict__ venue,           // (B,L)
    const int* __restrict__ team,            // (B,L)
    const int* __restrict__ opponent,        // (B,L)
    const int* __restrict__ result,          // (B,L)
    const int* __restrict__ next_venue,      // (B,)
    const int* __restrict__ next_team,       // (B,)
    const int* __restrict__ next_opponent,   // (B,)
    float* __restrict__ out)                 // (B,3)
{
    const int b    = blockIdx.x;
    const int t    = threadIdx.x;
    const int lane = t & 63;
    const int wid  = t >> 6;

    __shared__ float nc[384];       // next_cond: [venue | team | opponent] segments
    __shared__ int   s_idx[4][L_];  // venue, team, opponent, result indices
    __shared__ float s_attn[L_];
    __shared__ float s_gf[L_];
    __shared__ float s_ga[L_];
    __shared__ float s_red[8];      // 4-wave reduce scratch (max in [0..3], sum in [4..7])
    __shared__ float s_pr[517];     // past_repr (514) + stats (3)

    const int base = b * L_;
    s_idx[0][t] = venue[base + t];
    s_idx[1][t] = team[base + t];
    s_idx[2][t] = opponent[base + t];
    s_idx[3][t] = result[base + t];
    s_gf[t] = goals_for[base + t];
    s_ga[t] = goals_against[base + t];

    const int nv  = next_venue[b];
    const int ntm = next_team[b];
    const int nop = next_opponent[b];
    if (t < 128) {
        nc[t]       = venue_embed[nv * H_ + t];
        nc[128 + t] = team_embed[ntm * H_ + t];
    } else {
        nc[256 + (t - 128)] = team_embed[nop * H_ + (t - 128)];
    }
    __syncthreads();

    // ---- scores: each thread does a 384-length dot (3x128, float4 loads) ----
    const float4* vrow = (const float4*)(venue_embed + s_idx[0][t] * H_);
    const float4* trow = (const float4*)(team_embed  + s_idx[1][t] * H_);
    const float4* orow = (const float4*)(team_embed  + s_idx[2][t] * H_);
    const float4* ncv  = (const float4*)(nc);
    const float4* nct  = (const float4*)(nc + 128);
    const float4* nco  = (const float4*)(nc + 256);
    float s = 0.f;
    #pragma unroll
    for (int j = 0; j < 32; ++j) {
        float4 a, c;
        a = vrow[j]; c = ncv[j];
        s += a.x * c.x + a.y * c.y + a.z * c.z + a.w * c.w;
        a = trow[j]; c = nct[j];
        s += a.x * c.x + a.y * c.y + a.z * c.z + a.w * c.w;
        a = orow[j]; c = nco[j];
        s += a.x * c.x + a.y * c.y + a.z * c.z + a.w * c.w;
    }
    s *= 0.05103103630798287f;  // 1/sqrt(3*H) = 1/sqrt(384)

    // ---- softmax over L=256 (4 waves) ----
    float m = s;
    #pragma unroll
    for (int off = 32; off > 0; off >>= 1) m = fmaxf(m, __shfl_down(m, off));
    if (lane == 0) s_red[wid] = m;
    __syncthreads();
    m = fmaxf(fmaxf(s_red[0], s_red[1]), fmaxf(s_red[2], s_red[3]));

    const float e = expf(s - m);
    float sum = e;
    #pragma unroll
    for (int off = 32; off > 0; off >>= 1) sum += __shfl_down(sum, off);
    if (lane == 0) s_red[4 + wid] = sum;
    __syncthreads();
    sum = s_red[4] + s_red[5] + s_red[6] + s_red[7];

    s_attn[t] = e / sum;
    __syncthreads();

    // ---- past_repr: parallelize over the 514 dims ----
    // For a fixed l, a wave's lanes read the SAME table row at consecutive j
    // -> coalesced + cache-friendly; s_attn/idx reads are LDS broadcasts.
    for (int d = t; d < 514; d += 256) {
        float acc = 0.f;
        if (d < 512) {
            const int seg = d >> 7;   // 0:venue 1:team 2:opponent 3:result
            const int j   = d & 127;
            const float* tbl = (seg == 0) ? venue_embed
                             : (seg == 3) ? result_embed
                                          : team_embed;
            const int* idxs = s_idx[seg];
            #pragma unroll 4
            for (int l = 0; l < L_; ++l) {
                acc += s_attn[l] * tbl[idxs[l] * H_ + j];
            }
        } else {
            const float* g = (d == 512) ? s_gf : s_ga;
            for (int l = 0; l < L_; ++l) acc += s_attn[l] * g[l];
        }
        s_pr[d] = acc;
    }
    if (t < 3) s_pr[514 + t] = stats[b * 3 + t];
    __syncthreads();

    // ---- logits: wave r computes output r (517-length dot) ----
    if (wid < 3) {
        float acc = 0.f;
        for (int d = lane; d < 517; d += 64) acc += s_pr[d] * W_out[d * 3 + wid];
        #pragma unroll
        for (int off = 32; off > 0; off >>= 1) acc += __shfl_down(acc, off);
        if (lane == 0) out[b * 3 + wid] = acc + b_out[wid];
    }
}

extern "C" void kernel_launch(void* const* d_in, const int* in_sizes, int n_in,
                              void* d_out, int out_size, void* d_ws, size_t ws_size,
                              hipStream_t stream) {
    const float* team_embed    = (const float*)d_in[0];
    const float* venue_embed   = (const float*)d_in[1];
    const float* result_embed  = (const float*)d_in[2];
    const float* W_out         = (const float*)d_in[3];
    const float* b_out         = (const float*)d_in[4];
    const float* goals_for     = (const float*)d_in[5];
    const float* goals_against = (const float*)d_in[6];
    const float* stats         = (const float*)d_in[7];
    const int* venue           = (const int*)d_in[8];
    const int* team            = (const int*)d_in[9];
    const int* opponent        = (const int*)d_in[10];
    const int* result          = (const int*)d_in[11];
    const int* next_venue      = (const int*)d_in[12];
    const int* next_team       = (const int*)d_in[13];
    const int* next_opponent   = (const int*)d_in[14];
    float* out = (float*)d_out;

    const int B = in_sizes[12];  // next_venue has B elements
    fused_match_kernel<<<B, 256, 0, stream>>>(
        team_embed, venue_embed, result_embed, W_out, b_out,
        goals_for, goals_against, stats,
        venue, team, opponent, result,
        next_venue, next_team, next_opponent, out);
}

// Round 2
// 144.582 us; speedup vs baseline: 1.2725x; 1.2725x over previous
//
#include <hip/hip_runtime.h>

// Problem constants (match reference): B=1024, L=256, H=128
#define L_ 256
#define H_ 128

__global__ __launch_bounds__(256) void fused_match_kernel(
    const float* __restrict__ team_embed,    // (1000,128)
    const float* __restrict__ venue_embed,   // (3,128)
    const float* __restrict__ result_embed,  // (3,128)
    const float* __restrict__ W_out,         // (517,3)
    const float* __restrict__ b_out,         // (3,)
    const float* __restrict__ goals_for,     // (B,L)
    const float* __restrict__ goals_against, // (B,L)
    const float* __restrict__ stats,         // (B,3)
    const int* __restrict__ venue,           // (B,L)
    const int* __restrict__ team,            // (B,L)
    const int* __restrict__ opponent,        // (B,L)
    const int* __restrict__ result,          // (B,L)
    const int* __restrict__ next_venue,      // (B,)
    const int* __restrict__ next_team,       // (B,)
    const int* __restrict__ next_opponent,   // (B,)
    float* __restrict__ out)                 // (B,3)
{
    const int b    = blockIdx.x;
    const int t    = threadIdx.x;
    const int lane = t & 63;
    const int wid  = t >> 6;

    __shared__ float  nc[384];         // next_cond: [venue | team | opponent]
    __shared__ int    s_team[L_];
    __shared__ int    s_opp[L_];
    __shared__ float  s_attn[L_];
    __shared__ float  s_dotv[3];       // venue_embed[v] . nc_venue, v=0..2
    __shared__ float  s_redm[4];       // max partials
    __shared__ float  s_reds[4];       // sum partials
    __shared__ float  s_redw[4][8];    // e-weighted bucket/goal partials per wave
    __shared__ float  s_w[8];          // wv[0..2], wr[0..2], gf_sum, ga_sum (attn-weighted)
    __shared__ float4 s_part[4][64];   // team/opp partial accumulators
    __shared__ float  s_pr[517];       // past_repr (514) + stats (3)

    const int base = b * L_;
    const int my_venue  = venue[base + t];
    const int my_result = result[base + t];
    const float my_gf   = goals_for[base + t];
    const float my_ga   = goals_against[base + t];
    s_team[t] = team[base + t];
    s_opp[t]  = opponent[base + t];

    const int nv  = next_venue[b];
    const int ntm = next_team[b];
    const int nop = next_opponent[b];
    if (t < 128) {
        nc[t]       = venue_embed[nv * H_ + t];
        nc[128 + t] = team_embed[ntm * H_ + t];
    } else {
        nc[128 + t] = team_embed[nop * H_ + (t - 128)];  // 256..383
    }
    __syncthreads();

    // ---- precompute the 3 venue score dots (waves 0..2) ----
    if (wid < 3) {
        float a = venue_embed[wid * H_ + lane]      * nc[lane]
                + venue_embed[wid * H_ + 64 + lane] * nc[64 + lane];
        #pragma unroll
        for (int off = 32; off > 0; off >>= 1) a += __shfl_down(a, off);
        if (lane == 0) s_dotv[wid] = a;
    }

    // ---- team/opponent part of the score (float4 gathers) ----
    const float4* trow = (const float4*)(team_embed + s_team[t] * H_);
    const float4* orow = (const float4*)(team_embed + s_opp[t] * H_);
    const float4* nct  = (const float4*)(nc + 128);
    const float4* nco  = (const float4*)(nc + 256);
    float s = 0.f;
    #pragma unroll
    for (int j = 0; j < 32; ++j) {
        float4 a = trow[j], c = nct[j];
        s += a.x * c.x + a.y * c.y + a.z * c.z + a.w * c.w;
        a = orow[j]; c = nco[j];
        s += a.x * c.x + a.y * c.y + a.z * c.z + a.w * c.w;
    }
    __syncthreads();  // s_dotv visible
    s = (s + s_dotv[my_venue]) * 0.05103103630798287f;  // 1/sqrt(384)

    // ---- softmax max ----
    float m = s;
    #pragma unroll
    for (int off = 32; off > 0; off >>= 1) m = fmaxf(m, __shfl_down(m, off));
    if (lane == 0) s_redm[wid] = m;
    __syncthreads();
    m = fmaxf(fmaxf(s_redm[0], s_redm[1]), fmaxf(s_redm[2], s_redm[3]));

    const float e = expf(s - m);

    // ---- fused reductions: softmax sum + 6 bucket weights + 2 goal sums ----
    float vals[8];
    vals[0] = (my_venue  == 0) ? e : 0.f;
    vals[1] = (my_venue  == 1) ? e : 0.f;
    vals[2] = (my_venue  == 2) ? e : 0.f;
    vals[3] = (my_result == 0) ? e : 0.f;
    vals[4] = (my_result == 1) ? e : 0.f;
    vals[5] = (my_result == 2) ? e : 0.f;
    vals[6] = e * my_gf;
    vals[7] = e * my_ga;
    float sum = e;
    #pragma unroll
    for (int off = 32; off > 0; off >>= 1) {
        sum += __shfl_down(sum, off);
        #pragma unroll
        for (int k = 0; k < 8; ++k) vals[k] += __shfl_down(vals[k], off);
    }
    if (lane == 0) {
        s_reds[wid] = sum;
        #pragma unroll
        for (int k = 0; k < 8; ++k) s_redw[wid][k] = vals[k];
    }
    __syncthreads();
    sum = s_reds[0] + s_reds[1] + s_reds[2] + s_reds[3];
    s_attn[t] = e / sum;
    if (t < 8)
        s_w[t] = (s_redw[0][t] + s_redw[1][t] + s_redw[2][t] + s_redw[3][t]) / sum;
    __syncthreads();

    // ---- past_repr, team/opponent segments (the only real gathers left) ----
    // lane 0..31 -> team float4-col c, lane 32..63 -> opponent float4-col c;
    // wave wid handles L-quarter [wid*64, wid*64+64)
    {
        const int  segp = lane >> 5;
        const int  c    = lane & 31;
        const int* idxs = segp ? s_opp : s_team;
        const int  l0   = wid * 64;
        float4 acc = make_float4(0.f, 0.f, 0.f, 0.f);
        #pragma unroll 4
        for (int i = 0; i < 64; ++i) {
            const int   l = l0 + i;
            const float w = s_attn[l];
            const float4 v = ((const float4*)(team_embed + idxs[l] * H_))[c];
            acc.x += w * v.x; acc.y += w * v.y; acc.z += w * v.z; acc.w += w * v.w;
        }
        s_part[wid][lane] = acc;
    }
    __syncthreads();

    // ---- assemble past_repr (517) ----
    if (t < 64) {
        const float4 a0 = s_part[0][t], a1 = s_part[1][t], a2 = s_part[2][t], a3 = s_part[3][t];
        const int d = 128 + (t >> 5) * 128 + (t & 31) * 4;  // team: 128.., opp: 256..
        s_pr[d + 0] = a0.x + a1.x + a2.x + a3.x;
        s_pr[d + 1] = a0.y + a1.y + a2.y + a3.y;
        s_pr[d + 2] = a0.z + a1.z + a2.z + a3.z;
        s_pr[d + 3] = a0.w + a1.w + a2.w + a3.w;
        if (t < 2) s_pr[512 + t] = s_w[6 + t];                     // goals
        if (t >= 2 && t < 5) s_pr[512 + t] = stats[b * 3 + t - 2]; // stats -> 514..516
    } else if (t < 192) {
        const int j = t - 64;  // venue dims 0..127, bucketed 3-term combo
        s_pr[j] = s_w[0] * venue_embed[j] + s_w[1] * venue_embed[H_ + j]
                + s_w[2] * venue_embed[2 * H_ + j];
    } else {
        const int j = t - 192;  // result dims 384..511, two per thread
        s_pr[384 + j] = s_w[3] * result_embed[j]      + s_w[4] * result_embed[H_ + j]
                      + s_w[5] * result_embed[2 * H_ + j];
        s_pr[448 + j] = s_w[3] * result_embed[64 + j] + s_w[4] * result_embed[H_ + 64 + j]
                      + s_w[5] * result_embed[2 * H_ + 64 + j];
    }
    __syncthreads();

    // ---- logits: wave r computes output r (517-length dot) ----
    if (wid < 3) {
        float acc = 0.f;
        for (int d = lane; d < 517; d += 64) acc += s_pr[d] * W_out[d * 3 + wid];
        #pragma unroll
        for (int off = 32; off > 0; off >>= 1) acc += __shfl_down(acc, off);
        if (lane == 0) out[b * 3 + wid] = acc + b_out[wid];
    }
}

extern "C" void kernel_launch(void* const* d_in, const int* in_sizes, int n_in,
                              void* d_out, int out_size, void* d_ws, size_t ws_size,
                              hipStream_t stream) {
    const float* team_embed    = (const float*)d_in[0];
    const float* venue_embed   = (const float*)d_in[1];
    const float* result_embed  = (const float*)d_in[2];
    const float* W_out         = (const float*)d_in[3];
    const float* b_out         = (const float*)d_in[4];
    const float* goals_for     = (const float*)d_in[5];
    const float* goals_against = (const float*)d_in[6];
    const float* stats         = (const float*)d_in[7];
    const int* venue           = (const int*)d_in[8];
    const int* team            = (const int*)d_in[9];
    const int* opponent        = (const int*)d_in[10];
    const int* result          = (const int*)d_in[11];
    const int* next_venue      = (const int*)d_in[12];
    const int* next_team       = (const int*)d_in[13];
    const int* next_opponent   = (const int*)d_in[14];
    float* out = (float*)d_out;

    const int B = in_sizes[12];  // next_venue has B elements
    fused_match_kernel<<<B, 256, 0, stream>>>(
        team_embed, venue_embed, result_embed, W_out, b_out,
        goals_for, goals_against, stats,
        venue, team, opponent, result,
        next_venue, next_team, next_opponent, out);
}

// Round 3
// 118.077 us; speedup vs baseline: 1.5582x; 1.2245x over previous
//
#include <hip/hip_runtime.h>

// Problem constants (match reference): B=1024, L=256, H=128
#define L_ 256
#define H_ 128

__global__ __launch_bounds__(256) void fused_match_kernel(
    const float* __restrict__ team_embed,    // (1000,128)
    const float* __restrict__ venue_embed,   // (3,128)
    const float* __restrict__ result_embed,  // (3,128)
    const float* __restrict__ W_out,         // (517,3)
    const float* __restrict__ b_out,         // (3,)
    const float* __restrict__ goals_for,     // (B,L)
    const float* __restrict__ goals_against, // (B,L)
    const float* __restrict__ stats,         // (B,3)
    const int* __restrict__ venue,           // (B,L)
    const int* __restrict__ team,            // (B,L)
    const int* __restrict__ opponent,        // (B,L)
    const int* __restrict__ result,          // (B,L)
    const int* __restrict__ next_venue,      // (B,)
    const int* __restrict__ next_team,       // (B,)
    const int* __restrict__ next_opponent,   // (B,)
    float* __restrict__ out)                 // (B,3)
{
    const int b    = blockIdx.x;
    const int t    = threadIdx.x;
    const int lane = t & 63;
    const int wid  = t >> 6;

    __shared__ float  nc[384];         // next_cond: [venue | team | opponent]
    __shared__ int    s_team[L_];
    __shared__ int    s_opp[L_];
    __shared__ float  s_score[L_];
    __shared__ float  s_attn[L_];
    __shared__ float  s_dotv[3];       // venue_embed[v] . nc_venue, v=0..2
    __shared__ float  s_redm[4];       // max partials
    __shared__ float  s_reds[4];       // sum partials
    __shared__ float  s_redw[4][8];    // e-weighted bucket/goal partials per wave
    __shared__ float  s_w[8];          // wv[0..2], wr[0..2], gf_sum, ga_sum
    __shared__ float4 s_part[4][64];   // team/opp partial accumulators
    __shared__ float  s_pr[517];       // past_repr (514) + stats (3)

    const int base = b * L_;
    const int my_venue  = venue[base + t];
    const int my_result = result[base + t];
    const float my_gf   = goals_for[base + t];
    const float my_ga   = goals_against[base + t];
    s_team[t] = team[base + t];
    s_opp[t]  = opponent[base + t];

    const int nv  = next_venue[b];
    const int ntm = next_team[b];
    const int nop = next_opponent[b];
    if (t < 128) {
        nc[t]       = venue_embed[nv * H_ + t];
        nc[128 + t] = team_embed[ntm * H_ + t];
    } else {
        nc[128 + t] = team_embed[nop * H_ + (t - 128)];  // 256..383
    }
    __syncthreads();

    // ---- precompute the 3 venue score dots (waves 0..2) ----
    if (wid < 3) {
        float a = venue_embed[wid * H_ + lane]      * nc[lane]
                + venue_embed[wid * H_ + 64 + lane] * nc[64 + lane];
        #pragma unroll
        for (int off = 32; off > 0; off >>= 1) a += __shfl_down(a, off);
        if (lane == 0) s_dotv[wid] = a;
    }

    // ---- scores, COALESCED: wave wid handles l in [wid*64, wid*64+64).
    // lanes 0..31 read consecutive float4 of the TEAM row of l, lanes 32..63
    // the OPP row; per-lane nc element is loop-invariant (register). One
    // 6-step xor-butterfly reduces team+opp dot together -> s_score[l].
    {
        const int    c    = lane & 31;
        const float4 ncr  = ((const float4*)nc)[32 + lane];  // nct[c] or nco[c]
        const int*   ridx = (lane < 32) ? s_team : s_opp;
        const int    l0   = wid * 64;
        for (int i = 0; i < 64; i += 4) {
            float p0, p1, p2, p3;
            {
                const float4 v0 = ((const float4*)team_embed)[ridx[l0 + i + 0] * 32 + c];
                const float4 v1 = ((const float4*)team_embed)[ridx[l0 + i + 1] * 32 + c];
                const float4 v2 = ((const float4*)team_embed)[ridx[l0 + i + 2] * 32 + c];
                const float4 v3 = ((const float4*)team_embed)[ridx[l0 + i + 3] * 32 + c];
                p0 = v0.x * ncr.x + v0.y * ncr.y + v0.z * ncr.z + v0.w * ncr.w;
                p1 = v1.x * ncr.x + v1.y * ncr.y + v1.z * ncr.z + v1.w * ncr.w;
                p2 = v2.x * ncr.x + v2.y * ncr.y + v2.z * ncr.z + v2.w * ncr.w;
                p3 = v3.x * ncr.x + v3.y * ncr.y + v3.z * ncr.z + v3.w * ncr.w;
            }
            #pragma unroll
            for (int k = 32; k > 0; k >>= 1) {
                p0 += __shfl_xor(p0, k);
                p1 += __shfl_xor(p1, k);
                p2 += __shfl_xor(p2, k);
                p3 += __shfl_xor(p3, k);
            }
            if (lane == 0) {
                s_score[l0 + i + 0] = p0;
                s_score[l0 + i + 1] = p1;
                s_score[l0 + i + 2] = p2;
                s_score[l0 + i + 3] = p3;
            }
        }
    }
    __syncthreads();

    const float s = (s_score[t] + s_dotv[my_venue]) * 0.05103103630798287f;  // 1/sqrt(384)

    // ---- softmax max ----
    float m = s;
    #pragma unroll
    for (int off = 32; off > 0; off >>= 1) m = fmaxf(m, __shfl_down(m, off));
    if (lane == 0) s_redm[wid] = m;
    __syncthreads();
    m = fmaxf(fmaxf(s_redm[0], s_redm[1]), fmaxf(s_redm[2], s_redm[3]));

    const float e = expf(s - m);

    // ---- fused reductions: softmax sum + 6 bucket weights + 2 goal sums ----
    float vals[8];
    vals[0] = (my_venue  == 0) ? e : 0.f;
    vals[1] = (my_venue  == 1) ? e : 0.f;
    vals[2] = (my_venue  == 2) ? e : 0.f;
    vals[3] = (my_result == 0) ? e : 0.f;
    vals[4] = (my_result == 1) ? e : 0.f;
    vals[5] = (my_result == 2) ? e : 0.f;
    vals[6] = e * my_gf;
    vals[7] = e * my_ga;
    float sum = e;
    #pragma unroll
    for (int off = 32; off > 0; off >>= 1) {
        sum += __shfl_down(sum, off);
        #pragma unroll
        for (int k = 0; k < 8; ++k) vals[k] += __shfl_down(vals[k], off);
    }
    if (lane == 0) {
        s_reds[wid] = sum;
        #pragma unroll
        for (int k = 0; k < 8; ++k) s_redw[wid][k] = vals[k];
    }
    __syncthreads();
    sum = s_reds[0] + s_reds[1] + s_reds[2] + s_reds[3];
    s_attn[t] = e / sum;
    if (t < 8)
        s_w[t] = (s_redw[0][t] + s_redw[1][t] + s_redw[2][t] + s_redw[3][t]) / sum;
    __syncthreads();

    // ---- past_repr, team/opponent segments (coalesced gathers) ----
    {
        const int  segp = lane >> 5;
        const int  c    = lane & 31;
        const int* idxs = segp ? s_opp : s_team;
        const int  l0   = wid * 64;
        float4 acc = make_float4(0.f, 0.f, 0.f, 0.f);
        #pragma unroll 4
        for (int i = 0; i < 64; ++i) {
            const int   l = l0 + i;
            const float w = s_attn[l];
            const float4 v = ((const float4*)(team_embed + idxs[l] * H_))[c];
            acc.x += w * v.x; acc.y += w * v.y; acc.z += w * v.z; acc.w += w * v.w;
        }
        s_part[wid][lane] = acc;
    }
    __syncthreads();

    // ---- assemble past_repr (517) ----
    if (t < 64) {
        const float4 a0 = s_part[0][t], a1 = s_part[1][t], a2 = s_part[2][t], a3 = s_part[3][t];
        const int d = 128 + (t >> 5) * 128 + (t & 31) * 4;  // team: 128.., opp: 256..
        s_pr[d + 0] = a0.x + a1.x + a2.x + a3.x;
        s_pr[d + 1] = a0.y + a1.y + a2.y + a3.y;
        s_pr[d + 2] = a0.z + a1.z + a2.z + a3.z;
        s_pr[d + 3] = a0.w + a1.w + a2.w + a3.w;
        if (t < 2) s_pr[512 + t] = s_w[6 + t];                     // goals
        if (t >= 2 && t < 5) s_pr[512 + t] = stats[b * 3 + t - 2]; // stats -> 514..516
    } else if (t < 192) {
        const int j = t - 64;  // venue dims 0..127, bucketed 3-term combo
        s_pr[j] = s_w[0] * venue_embed[j] + s_w[1] * venue_embed[H_ + j]
                + s_w[2] * venue_embed[2 * H_ + j];
    } else {
        const int j = t - 192;  // result dims 384..511, two per thread
        s_pr[384 + j] = s_w[3] * result_embed[j]      + s_w[4] * result_embed[H_ + j]
                      + s_w[5] * result_embed[2 * H_ + j];
        s_pr[448 + j] = s_w[3] * result_embed[64 + j] + s_w[4] * result_embed[H_ + 64 + j]
                      + s_w[5] * result_embed[2 * H_ + 64 + j];
    }
    __syncthreads();

    // ---- logits: wave r computes output r (517-length dot) ----
    if (wid < 3) {
        float acc = 0.f;
        for (int d = lane; d < 517; d += 64) acc += s_pr[d] * W_out[d * 3 + wid];
        #pragma unroll
        for (int off = 32; off > 0; off >>= 1) acc += __shfl_down(acc, off);
        if (lane == 0) out[b * 3 + wid] = acc + b_out[wid];
    }
}

extern "C" void kernel_launch(void* const* d_in, const int* in_sizes, int n_in,
                              void* d_out, int out_size, void* d_ws, size_t ws_size,
                              hipStream_t stream) {
    const float* team_embed    = (const float*)d_in[0];
    const float* venue_embed   = (const float*)d_in[1];
    const float* result_embed  = (const float*)d_in[2];
    const float* W_out         = (const float*)d_in[3];
    const float* b_out         = (const float*)d_in[4];
    const float* goals_for     = (const float*)d_in[5];
    const float* goals_against = (const float*)d_in[6];
    const float* stats         = (const float*)d_in[7];
    const int* venue           = (const int*)d_in[8];
    const int* team            = (const int*)d_in[9];
    const int* opponent        = (const int*)d_in[10];
    const int* result          = (const int*)d_in[11];
    const int* next_venue      = (const int*)d_in[12];
    const int* next_team       = (const int*)d_in[13];
    const int* next_opponent   = (const int*)d_in[14];
    float* out = (float*)d_out;

    const int B = in_sizes[12];  // next_venue has B elements
    fused_match_kernel<<<B, 256, 0, stream>>>(
        team_embed, venue_embed, result_embed, W_out, b_out,
        goals_for, goals_against, stats,
        venue, team, opponent, result,
        next_venue, next_team, next_opponent, out);
}

// Round 4
// 108.228 us; speedup vs baseline: 1.7000x; 1.0910x over previous
//
#include <hip/hip_runtime.h>

// Problem constants (match reference): B=1024, L=256, H=128
#define L_ 256
#define H_ 128

// base-2 softmax scale: (1/sqrt(384)) * log2(e)
#define KSCALE 0.07362222315f

__global__ __launch_bounds__(256) void fused_match_kernel(
    const float* __restrict__ team_embed,    // (1000,128)
    const float* __restrict__ venue_embed,   // (3,128)
    const float* __restrict__ result_embed,  // (3,128)
    const float* __restrict__ W_out,         // (517,3)
    const float* __restrict__ b_out,         // (3,)
    const float* __restrict__ goals_for,     // (B,L)
    const float* __restrict__ goals_against, // (B,L)
    const float* __restrict__ stats,         // (B,3)
    const int* __restrict__ venue,           // (B,L)
    const int* __restrict__ team,            // (B,L)
    const int* __restrict__ opponent,        // (B,L)
    const int* __restrict__ result,          // (B,L)
    const int* __restrict__ next_venue,      // (B,)
    const int* __restrict__ next_team,       // (B,)
    const int* __restrict__ next_opponent,   // (B,)
    float* __restrict__ out)                 // (B,3)
{
    const int b    = blockIdx.x;
    const int t    = threadIdx.x;
    const int lane = t & 63;
    const int wid  = t >> 6;
    const int half = lane >> 5;   // 0: lanes 0-31, 1: lanes 32-63
    const int c    = lane & 31;   // float4 column within a 128-float row

    __shared__ float  nc[384];         // next_cond: [venue | team | opponent]
    __shared__ int    s_team[L_];
    __shared__ int    s_opp[L_];
    __shared__ float  s_score[L_];     // base-2 scaled scores kk
    __shared__ float  s_dv[L_];        // venue-dot addend per l (raw units)
    __shared__ float  s_dotv[3];
    __shared__ float  s_m[8];          // per-half running max (8 = 4 waves x 2 halves)
    __shared__ float4 s_accT[8][32];   // per-half team-seg accumulators
    __shared__ float4 s_accO[8][32];   // per-half opp-seg accumulators
    __shared__ float  s_reds[4];
    __shared__ float  s_redw[4][8];
    __shared__ float  s_w[8];          // wv[0..2], wr[0..2], gf_sum, ga_sum (normalized)
    __shared__ float  s_pr[517];

    const int base = b * L_;
    const int my_venue  = venue[base + t];
    const int my_result = result[base + t];
    const float my_gf   = goals_for[base + t];
    const float my_ga   = goals_against[base + t];
    s_team[t] = team[base + t];
    s_opp[t]  = opponent[base + t];

    const int nv  = next_venue[b];
    const int ntm = next_team[b];
    const int nop = next_opponent[b];
    if (t < 128) {
        nc[t]       = venue_embed[nv * H_ + t];
        nc[128 + t] = team_embed[ntm * H_ + t];
    } else {
        nc[128 + t] = team_embed[nop * H_ + (t - 128)];  // 256..383
    }
    __syncthreads();

    // ---- the 3 venue score dots (waves 0..2) ----
    if (wid < 3) {
        float a = venue_embed[wid * H_ + lane]      * nc[lane]
                + venue_embed[wid * H_ + 64 + lane] * nc[64 + lane];
        #pragma unroll
        for (int off = 32; off > 0; off >>= 1) a += __shfl_down(a, off);
        if (lane == 0) s_dotv[wid] = a;
    }
    __syncthreads();
    s_dv[t] = s_dotv[my_venue];
    __syncthreads();

    // ---- fused single-pass: score + online softmax + weighted row accumulate.
    // Half-wave h of wave wid handles l in [wid*64 + h*32, +32). Per load instr
    // the two halves read two different rows (16 cache lines, coalesced).
    const float4 nct_c = ((const float4*)(nc + 128))[c];
    const float4 nco_c = ((const float4*)(nc + 256))[c];
    const int    lb    = wid * 64 + half * 32;
    float4 accT = make_float4(0.f, 0.f, 0.f, 0.f);
    float4 accO = make_float4(0.f, 0.f, 0.f, 0.f);
    float  mrun = -1e30f;
    #pragma unroll 4
    for (int i = 0; i < 32; ++i) {
        const int l = lb + i;
        const float4 vT = ((const float4*)team_embed)[s_team[l] * 32 + c];
        const float4 vO = ((const float4*)team_embed)[s_opp[l]  * 32 + c];
        float p = vT.x * nct_c.x + vT.y * nct_c.y + vT.z * nct_c.z + vT.w * nct_c.w
                + vO.x * nco_c.x + vO.y * nco_c.y + vO.z * nco_c.z + vO.w * nco_c.w;
        // reduce across the 32 lanes of this half (result in all 32 lanes)
        #pragma unroll
        for (int k = 16; k > 0; k >>= 1) p += __shfl_xor(p, k);
        const float kk = (p + s_dv[l]) * KSCALE;   // base-2 scaled score
        if ((lane & 31) == 0) s_score[l] = kk;
        if (kk > mrun) {                           // half-uniform, rare
            const float alpha = exp2f(mrun - kk);
            accT.x *= alpha; accT.y *= alpha; accT.z *= alpha; accT.w *= alpha;
            accO.x *= alpha; accO.y *= alpha; accO.z *= alpha; accO.w *= alpha;
            mrun = kk;
        }
        const float e = exp2f(kk - mrun);
        accT.x += e * vT.x; accT.y += e * vT.y; accT.z += e * vT.z; accT.w += e * vT.w;
        accO.x += e * vO.x; accO.y += e * vO.y; accO.z += e * vO.z; accO.w += e * vO.w;
    }
    {
        const int hw = wid * 2 + half;
        if ((lane & 31) == 0) s_m[hw] = mrun;
        s_accT[hw][c] = accT;
        s_accO[hw][c] = accO;
    }
    __syncthreads();

    // ---- global max over the 8 half-states ----
    float M = s_m[0];
    #pragma unroll
    for (int j = 1; j < 8; ++j) M = fmaxf(M, s_m[j]);

    // ---- bucket pass: softmax denom Z + 6 bucket weights + 2 goal sums ----
    const float e = exp2f(s_score[t] - M);
    float vals[8];
    vals[0] = (my_venue  == 0) ? e : 0.f;
    vals[1] = (my_venue  == 1) ? e : 0.f;
    vals[2] = (my_venue  == 2) ? e : 0.f;
    vals[3] = (my_result == 0) ? e : 0.f;
    vals[4] = (my_result == 1) ? e : 0.f;
    vals[5] = (my_result == 2) ? e : 0.f;
    vals[6] = e * my_gf;
    vals[7] = e * my_ga;
    float sum = e;
    #pragma unroll
    for (int off = 32; off > 0; off >>= 1) {
        sum += __shfl_down(sum, off);
        #pragma unroll
        for (int k = 0; k < 8; ++k) vals[k] += __shfl_down(vals[k], off);
    }
    if (lane == 0) {
        s_reds[wid] = sum;
        #pragma unroll
        for (int k = 0; k < 8; ++k) s_redw[wid][k] = vals[k];
    }
    __syncthreads();
    const float Z    = s_reds[0] + s_reds[1] + s_reds[2] + s_reds[3];
    const float invZ = 1.f / Z;
    if (t < 8)
        s_w[t] = (s_redw[0][t] + s_redw[1][t] + s_redw[2][t] + s_redw[3][t]) * invZ;
    __syncthreads();

    // ---- assemble past_repr (517) ----
    if (t < 64) {
        const int seg = t >> 5;   // 0: team dims 128.., 1: opp dims 256..
        const int cc  = t & 31;
        float4 a = make_float4(0.f, 0.f, 0.f, 0.f);
        #pragma unroll
        for (int h = 0; h < 8; ++h) {
            const float sc  = exp2f(s_m[h] - M);
            const float4 v  = seg ? s_accO[h][cc] : s_accT[h][cc];
            a.x += sc * v.x; a.y += sc * v.y; a.z += sc * v.z; a.w += sc * v.w;
        }
        const int d = 128 + seg * 128 + cc * 4;
        s_pr[d + 0] = a.x * invZ;
        s_pr[d + 1] = a.y * invZ;
        s_pr[d + 2] = a.z * invZ;
        s_pr[d + 3] = a.w * invZ;
        if (t < 2) s_pr[512 + t] = s_w[6 + t];                     // goals
        if (t >= 2 && t < 5) s_pr[512 + t] = stats[b * 3 + t - 2]; // stats 514..516
    } else if (t < 192) {
        const int j = t - 64;  // venue dims 0..127, bucketed 3-term combo
        s_pr[j] = s_w[0] * venue_embed[j] + s_w[1] * venue_embed[H_ + j]
                + s_w[2] * venue_embed[2 * H_ + j];
    } else {
        const int j = t - 192;  // result dims 384..511, two per thread
        s_pr[384 + j] = s_w[3] * result_embed[j]      + s_w[4] * result_embed[H_ + j]
                      + s_w[5] * result_embed[2 * H_ + j];
        s_pr[448 + j] = s_w[3] * result_embed[64 + j] + s_w[4] * result_embed[H_ + 64 + j]
                      + s_w[5] * result_embed[2 * H_ + 64 + j];
    }
    __syncthreads();

    // ---- logits: wave r computes output r (517-length dot) ----
    if (wid < 3) {
        float acc = 0.f;
        for (int d = lane; d < 517; d += 64) acc += s_pr[d] * W_out[d * 3 + wid];
        #pragma unroll
        for (int off = 32; off > 0; off >>= 1) acc += __shfl_down(acc, off);
        if (lane == 0) out[b * 3 + wid] = acc + b_out[wid];
    }
}

extern "C" void kernel_launch(void* const* d_in, const int* in_sizes, int n_in,
                              void* d_out, int out_size, void* d_ws, size_t ws_size,
                              hipStream_t stream) {
    const float* team_embed    = (const float*)d_in[0];
    const float* venue_embed   = (const float*)d_in[1];
    const float* result_embed  = (const float*)d_in[2];
    const float* W_out         = (const float*)d_in[3];
    const float* b_out         = (const float*)d_in[4];
    const float* goals_for     = (const float*)d_in[5];
    const float* goals_against = (const float*)d_in[6];
    const float* stats         = (const float*)d_in[7];
    const int* venue           = (const int*)d_in[8];
    const int* team            = (const int*)d_in[9];
    const int* opponent        = (const int*)d_in[10];
    const int* result          = (const int*)d_in[11];
    const int* next_venue      = (const int*)d_in[12];
    const int* next_team       = (const int*)d_in[13];
    const int* next_opponent   = (const int*)d_in[14];
    float* out = (float*)d_out;

    const int B = in_sizes[12];  // next_venue has B elements
    fused_match_kernel<<<B, 256, 0, stream>>>(
        team_embed, venue_embed, result_embed, W_out, b_out,
        goals_for, goals_against, stats,
        venue, team, opponent, result,
        next_venue, next_team, next_opponent, out);
}